// Round 23
// baseline (62.980 us; speedup 1.0000x reference)
//
#include <hip/hip_runtime.h>
#include <hip/hip_bf16.h>

#define N_ROWS 8192
#define DIMS   128

typedef __bf16 bf16x8 __attribute__((ext_vector_type(8)));
typedef float  f32x4  __attribute__((ext_vector_type(4)));

struct alignas(8) B4 { __hip_bfloat16 h0, h1, h2, h3; };

// xor-min across the 16 lanes of a DPP row, pure VALU (no DS pipe).
template <int CTRL>
__device__ __forceinline__ float fmin_dpp(float v) {
    int o = __builtin_amdgcn_update_dpp(0, __float_as_int(v), CTRL, 0xF, 0xF, true);
    return fminf(v, __int_as_float(o));
}

// ---------------------------------------------------------------------------
// prep: 256 blocks; blocks 0..127 -> cluster1 (bf16 copy scaled by -2),
// 128..255 -> cluster2 (scale +1). BOTH stored ROW-SWIZZLED with the full
// 4-bit row (elem ^= (row&15)<<3) because dist v18 stages BOTH tiles to LDS
// linearly via global_load_lds and ds_reads them with the same XOR ->
// conflict-spread ds_read_b128. Row sq-norms + per-block partial col stats.
// part layout: part[(sec*128+col)*128 + blk], sec 0=cs1, 1=cq1, 2=cs2.
// Also zeroes the tail ticket counter.
// ---------------------------------------------------------------------------
__global__ __launch_bounds__(256) void prep_k(const float* __restrict__ c1,
                                              const float* __restrict__ c2,
                                              __hip_bfloat16* __restrict__ c1b,
                                              __hip_bfloat16* __restrict__ c2b,
                                              float* __restrict__ sq1,
                                              float* __restrict__ sq2,
                                              float* __restrict__ part,
                                              int* __restrict__ cnt) {
    const int tid  = threadIdx.x;
    const int lane = tid & 63;
    const int wave = tid >> 6;
    const int half = lane >> 5;           // 0: even row, 1: odd row
    const int l32  = lane & 31;           // cols 4*l32 .. 4*l32+3
    const int cl   = blockIdx.x >> 7;     // 0 = cluster1, 1 = cluster2
    const int blk  = blockIdx.x & 127;

    if (blockIdx.x == 0 && tid == 0) *cnt = 0;

    const float* __restrict__ src    = cl ? c2 : c1;
    __hip_bfloat16* __restrict__ dst = cl ? c2b : c1b;
    float* __restrict__ sq           = cl ? sq2 : sq1;
    const float scale                = cl ? 1.0f : -2.0f;

    float4 cs = {0.f, 0.f, 0.f, 0.f};
    float4 cq = {0.f, 0.f, 0.f, 0.f};

    #pragma unroll 4
    for (int i = 0; i < 8; ++i) {
        const int row = blk * 64 + wave * 16 + i * 2 + half;
        float4 x = *reinterpret_cast<const float4*>(src + (size_t)row * DIMS + l32 * 4);
        B4 b4{__float2bfloat16(scale * x.x), __float2bfloat16(scale * x.y),
              __float2bfloat16(scale * x.z), __float2bfloat16(scale * x.w)};
        const int eoff = (l32 * 4) ^ ((row & 15) << 3);   // both clusters swizzled
        *reinterpret_cast<B4*>(dst + (size_t)row * DIMS + eoff) = b4;
        float s = x.x * x.x + x.y * x.y + x.z * x.z + x.w * x.w;
        #pragma unroll
        for (int m = 16; m; m >>= 1) s += __shfl_xor(s, m);   // within 32-lane half
        if (l32 == 0) sq[row] = s;
        cs.x += x.x; cs.y += x.y; cs.z += x.z; cs.w += x.w;
        cq.x += x.x * x.x; cq.y += x.y * x.y; cq.z += x.z * x.z; cq.w += x.w * x.w;
    }

    cs.x += __shfl_xor(cs.x, 32); cs.y += __shfl_xor(cs.y, 32);
    cs.z += __shfl_xor(cs.z, 32); cs.w += __shfl_xor(cs.w, 32);
    cq.x += __shfl_xor(cq.x, 32); cq.y += __shfl_xor(cq.y, 32);
    cq.z += __shfl_xor(cq.z, 32); cq.w += __shfl_xor(cq.w, 32);

    __shared__ float4 lds4[4][32];
    lds4[wave][l32] = cs;
    __syncthreads();
    if (tid < 32) {
        float4 a = lds4[0][tid], b = lds4[1][tid], c = lds4[2][tid], d = lds4[3][tid];
        float4 t = {a.x + b.x + c.x + d.x, a.y + b.y + c.y + d.y,
                    a.z + b.z + c.z + d.z, a.w + b.w + c.w + d.w};
        const int base = cl ? 32768 : 0;
        part[base + (4 * tid + 0) * 128 + blk] = t.x;
        part[base + (4 * tid + 1) * 128 + blk] = t.y;
        part[base + (4 * tid + 2) * 128 + blk] = t.z;
        part[base + (4 * tid + 3) * 128 + blk] = t.w;
    }
    __syncthreads();
    lds4[wave][l32] = cq;
    __syncthreads();
    if (tid < 32 && cl == 0) {
        float4 a = lds4[0][tid], b = lds4[1][tid], c = lds4[2][tid], d = lds4[3][tid];
        float4 t = {a.x + b.x + c.x + d.x, a.y + b.y + c.y + d.y,
                    a.z + b.z + c.z + d.z, a.w + b.w + c.w + d.w};
        part[16384 + (4 * tid + 0) * 128 + blk] = t.x;
        part[16384 + (4 * tid + 1) * 128 + blk] = t.y;
        part[16384 + (4 * tid + 2) * 128 + blk] = t.z;
        part[16384 + (4 * tid + 3) * 128 + blk] = t.w;
    }
}

// ---------------------------------------------------------------------------
// dist v18: BOTH-OPERANDS-FROM-LDS with 8-wave blocks — the unexplored
// fits-in-60-VGPRs + high-TLP corner. 22-round dichotomy: >60 VGPRs of
// long-lived operands -> constant L2-reload tax (pins spill / no-pins
// remat, attributes irrelevant); fits-60 tried only at 2 waves/SIMD (r16,
// 53.3). This: 512 threads, 128x128 tile, A(32KB)+B(32KB) staged linearly
// from pre-swizzled global; wave owns 64x32 (wr=wv>>2, wc=wv&3). Per
// ks=0..3: 4 A + 2 B ds_read_b128 -> 8 MFMAs into acc[4][2] (AGPR-pinned;
// C-in = sq2[col], c1b pre-scaled -2 -> acc = sq2 - 2*c1.c2). VGPR demand
// ~46 (a 16 + b 8 + addr/misc) << 60 grant: provably nothing to spill,
// ZERO global loads in the loop. 64KB LDS -> 2 blocks/CU -> 16 waves/CU
// = 4 waves/SIMD. Grid 64x64 = 4096. Epilogue: ct-min -> DPP 16-lane min
// -> pmin[row*256 + cg*4 + wc] (one write per slot).
// Expected binder: LDS throughput (~786 MB reads + 256 MB staging ~ 15us).
// MFMA 16x16x32 bf16 layouts (validated: absmax 0.0):
//   A: row = lane&15, k = (lane>>4)*8 + j
//   B: col = lane&15, k = (lane>>4)*8 + j
//   D: col = lane&15, row = (lane>>4)*4 + r
// ---------------------------------------------------------------------------
__global__ __attribute__((amdgpu_flat_work_group_size(512, 512),
                          amdgpu_waves_per_eu(2, 4)))
void dist_k(const __hip_bfloat16* __restrict__ c1bs,   // swizzled, scaled -2
            const __hip_bfloat16* __restrict__ c2bs,   // swizzled
            const float* __restrict__ sq2,
            float* __restrict__ pmin) {
    __shared__ uint4 smem4[4096];                      // 64 KB: A @0, B @32768
    char* smem = (char*)smem4;

    const int tid  = threadIdx.x;
    const int lane = tid & 63;
    const int wv   = tid >> 6;            // 0..7
    const int lo = lane & 15;
    const int hi = lane >> 4;
    const int rg = blockIdx.x >> 6;       // 0..63 : 128-row group
    const int cg = blockIdx.x & 63;       // 0..63 : 128-col group
    const int row0 = rg * 128;
    const int col0 = cg * 128;
    const int wr = wv >> 2;               // 0..1 : 64-row half
    const int wc = wv & 3;                // 0..3 : 32-col quarter

    // Stage A rows and B cols (both pre-swizzled -> linear copies).
    {
        const char* gA = (const char*)c1bs + (size_t)row0 * 256;
        const char* gB = (const char*)c2bs + (size_t)col0 * 256;
        #pragma unroll
        for (int i = 0; i < 4; ++i) {
            const int off = i * 8192 + wv * 1024;      // wave-uniform LDS dest
            __builtin_amdgcn_global_load_lds(
                (const __attribute__((address_space(1))) unsigned int*)
                    (const void*)(gA + off + lane * 16),
                (__attribute__((address_space(3))) unsigned int*)
                    (void*)(smem + off), 16, 0, 0);
            __builtin_amdgcn_global_load_lds(
                (const __attribute__((address_space(1))) unsigned int*)
                    (const void*)(gB + off + lane * 16),
                (__attribute__((address_space(3))) unsigned int*)
                    (void*)(smem + 32768 + off), 16, 0, 0);
        }
    }

    // C-in seeds: sq2 for this wave's cols (col = col0 + wc*32 + ct*16 + lo).
    float sq2t[2];
    #pragma unroll
    for (int ct = 0; ct < 2; ++ct)
        sq2t[ct] = sq2[col0 + wc * 32 + ct * 16 + lo];

    f32x4 acc[4][2];
    #pragma unroll
    for (int rt = 0; rt < 4; ++rt)
        #pragma unroll
        for (int ct = 0; ct < 2; ++ct)
            acc[rt][ct] = f32x4{sq2t[ct], sq2t[ct], sq2t[ct], sq2t[ct]};

    // Anchor the accumulators in the AGPR file (MFMA reads/writes C/D there
    // natively) — removes 32 regs from the arch-VGPR demand.
    #pragma unroll
    for (int rt = 0; rt < 4; ++rt)
        #pragma unroll
        for (int ct = 0; ct < 2; ++ct)
            asm volatile("" : "+a"(acc[rt][ct]));

    asm volatile("s_waitcnt vmcnt(0)" ::: "memory");
    __syncthreads();

    const int swz = lo << 4;              // full 4-bit row swizzle (row&15 == lo)
    #pragma unroll
    for (int ks = 0; ks < 4; ++ks) {
        bf16x8 a[4], b[2];
        #pragma unroll
        for (int rt = 0; rt < 4; ++rt) {
            const int row = wr * 64 + rt * 16 + lo;
            a[rt] = *reinterpret_cast<const bf16x8*>(
                smem + row * 256 + ((ks * 64 + hi * 16) ^ swz));
        }
        #pragma unroll
        for (int ct = 0; ct < 2; ++ct) {
            const int col = wc * 32 + ct * 16 + lo;
            b[ct] = *reinterpret_cast<const bf16x8*>(
                smem + 32768 + col * 256 + ((ks * 64 + hi * 16) ^ swz));
        }
        #pragma unroll
        for (int rt = 0; rt < 4; ++rt)
            #pragma unroll
            for (int ct = 0; ct < 2; ++ct)
                acc[rt][ct] = __builtin_amdgcn_mfma_f32_16x16x32_bf16(
                    a[rt], b[ct], acc[rt][ct], 0, 0, 0);
    }

    // Epilogue: min over the wave's 32 cols, DPP fold, one write per row.
    #pragma unroll
    for (int rt = 0; rt < 4; ++rt) {
        float mrow[4];
        #pragma unroll
        for (int r = 0; r < 4; ++r) {
            float v = fminf(acc[rt][0][r], acc[rt][1][r]);
            v = fmin_dpp<0xB1>(v);     // xor1
            v = fmin_dpp<0x4E>(v);     // xor2
            v = fmin_dpp<0x141>(v);    // row_half_mirror
            v = fmin_dpp<0x140>(v);    // row_mirror
            mrow[r] = v;
        }
        if (lo == 0) {
            #pragma unroll
            for (int r = 0; r < 4; ++r) {
                const int row = row0 + wr * 64 + rt * 16 + hi * 4 + r;
                pmin[(size_t)row * 256 + cg * 4 + wc] = mrow[r];
            }
        }
    }
}

// ---------------------------------------------------------------------------
// tail (fused reduce + finalize): 32 blocks x 256 threads.
// Each block: (a) thread = one row -> min of 256 partials + sq1, block-sum
// -> rscratch[b]; (b) threads 0..11 each sum one column-stat job.
// Device-scope ticket: LAST block combines in fixed order -> out[0].
// cnt is zeroed by prep_k each call.
// ---------------------------------------------------------------------------
__global__ __launch_bounds__(256) void tail_k(const float* __restrict__ pmin,
                                              const float* __restrict__ sq1,
                                              const float* __restrict__ part,
                                              float* __restrict__ rscratch,
                                              float* __restrict__ cscratch,
                                              int* __restrict__ cnt,
                                              float* __restrict__ out) {
    __shared__ float red[256];
    __shared__ int is_last;
    const int b   = blockIdx.x;
    const int tid = threadIdx.x;

    // (a) row-min fold over 256 partials (64 float4)
    const int row = b * 256 + tid;
    const float4* p = reinterpret_cast<const float4*>(pmin + (size_t)row * 256);
    float4 m4 = p[0];
    #pragma unroll 8
    for (int i = 1; i < 64; ++i) {
        float4 v = p[i];
        m4.x = fminf(m4.x, v.x); m4.y = fminf(m4.y, v.y);
        m4.z = fminf(m4.z, v.z); m4.w = fminf(m4.w, v.w);
    }
    float m = fminf(fminf(m4.x, m4.y), fminf(m4.z, m4.w)) + sq1[row];

    red[tid] = m;
    __syncthreads();
    for (int off = 128; off; off >>= 1) {
        if (tid < off) red[tid] += red[tid + off];
        __syncthreads();
    }
    if (tid == 0) rscratch[b] = red[0];

    // (b) column-stat jobs
    if (tid < 12) {
        const int j = b * 12 + tid;
        const float4* q = reinterpret_cast<const float4*>(part + j * 128);
        float4 a = {0.f, 0.f, 0.f, 0.f};
        #pragma unroll 8
        for (int k = 0; k < 32; ++k) {
            float4 v = q[k];
            a.x += v.x; a.y += v.y; a.z += v.z; a.w += v.w;
        }
        cscratch[j] = a.x + a.y + a.z + a.w;
    }

    // ticket
    __threadfence();
    __syncthreads();
    if (tid == 0) {
        int old = atomicAdd(cnt, 1);
        is_last = (old == 31) ? 1 : 0;
    }
    __syncthreads();
    if (!is_last) return;
    __threadfence();

    // finisher: combine in fixed order (deterministic)
    float s = (tid < 32) ? atomicAdd(&rscratch[tid], 0.0f) : 0.0f;

    float mm = 0.f;
    if (tid < DIMS) {
        float cs1 = atomicAdd(&cscratch[tid], 0.0f);
        float cq1 = atomicAdd(&cscratch[128 + tid], 0.0f);
        float cs2 = atomicAdd(&cscratch[256 + tid], 0.0f);
        const float inv_n = 1.0f / N_ROWS;
        float m1 = cs1 * inv_n;
        float m2 = cs2 * inv_n;
        float d  = m1 - m2;
        float var = cq1 * inv_n - m1 * m1;
        mm = d * d + fmaxf(0.1f - var, 0.0f);
    }

    __syncthreads();           // red[] reuse
    red[tid] = s * (1.0f / N_ROWS) + mm * (1.0f / DIMS);
    __syncthreads();
    for (int off = 128; off; off >>= 1) {
        if (tid < off) red[tid] += red[tid + off];
        __syncthreads();
    }
    if (tid == 0) out[0] = red[0];
}

// ---------------------------------------------------------------------------
extern "C" void kernel_launch(void* const* d_in, const int* in_sizes, int n_in,
                              void* d_out, int out_size, void* d_ws, size_t ws_size,
                              hipStream_t stream) {
    (void)in_sizes; (void)n_in; (void)out_size; (void)ws_size;
    const float* c1 = (const float*)d_in[0];
    const float* c2 = (const float*)d_in[1];

    char* ws = (char*)d_ws;
    __hip_bfloat16* c1b = (__hip_bfloat16*)ws;                    // 2 MB (swizzled)
    __hip_bfloat16* c2b = (__hip_bfloat16*)(ws + (1u << 21));     // 2 MB (swizzled)
    float* sq1          = (float*)(ws + (1u << 22));              // 32 KB
    float* sq2          = sq1 + N_ROWS;                           // 32 KB
    float* pmin         = sq2 + N_ROWS;                           // 8 MB
    float* part         = pmin + (size_t)N_ROWS * 256;            // 192 KB
    float* rscratch     = part + 3 * 16384;                       // 128 B
    float* cscratch     = rscratch + 32;                          // 1.5 KB
    int*   cnt          = (int*)(cscratch + 384);                 // 4 B

    prep_k<<<256, 256, 0, stream>>>(c1, c2, c1b, c2b, sq1, sq2, part, cnt);
    dist_k<<<4096, 512, 0, stream>>>(c1b, c2b, sq2, pmin);
    tail_k<<<32, 256, 0, stream>>>(pmin, sq1, part, rscratch, cscratch, cnt,
                                   (float*)d_out);
}

// Round 24
// 46.477 us; speedup vs baseline: 1.3551x; 1.3551x over previous
//
#include <hip/hip_runtime.h>
#include <hip/hip_bf16.h>

#define N_ROWS 8192
#define DIMS   128

typedef __bf16 bf16x8 __attribute__((ext_vector_type(8)));
typedef float  f32x4  __attribute__((ext_vector_type(4)));

struct alignas(8) B4 { __hip_bfloat16 h0, h1, h2, h3; };

// xor-min across the 16 lanes of a DPP row, pure VALU (no DS pipe).
template <int CTRL>
__device__ __forceinline__ float fmin_dpp(float v) {
    int o = __builtin_amdgcn_update_dpp(0, __float_as_int(v), CTRL, 0xF, 0xF, true);
    return fminf(v, __int_as_float(o));
}

// ---------------------------------------------------------------------------
// prep: 256 blocks; blocks 0..127 -> cluster1 (bf16 copy scaled by -2,
// stored ROW-SWIZZLED with the full 4-bit row: elem ^= (row&15)<<3, so dist
// stages LINEARLY with global_load_lds and ds_reads spread over 16 distinct
// 16B slots), 128..255 -> cluster2 (scale +1, LINEAR — consumed as register
// fragments). Row sq-norms + partial col stats.
// part layout: part[(sec*128+col)*128 + blk], sec 0=cs1, 1=cq1, 2=cs2.
// Also zeroes the tail ticket counter.
// ---------------------------------------------------------------------------
__global__ __launch_bounds__(256) void prep_k(const float* __restrict__ c1,
                                              const float* __restrict__ c2,
                                              __hip_bfloat16* __restrict__ c1b,
                                              __hip_bfloat16* __restrict__ c2b,
                                              float* __restrict__ sq1,
                                              float* __restrict__ sq2,
                                              float* __restrict__ part,
                                              int* __restrict__ cnt) {
    const int tid  = threadIdx.x;
    const int lane = tid & 63;
    const int wave = tid >> 6;
    const int half = lane >> 5;           // 0: even row, 1: odd row
    const int l32  = lane & 31;           // cols 4*l32 .. 4*l32+3
    const int cl   = blockIdx.x >> 7;     // 0 = cluster1, 1 = cluster2
    const int blk  = blockIdx.x & 127;

    if (blockIdx.x == 0 && tid == 0) *cnt = 0;

    const float* __restrict__ src    = cl ? c2 : c1;
    __hip_bfloat16* __restrict__ dst = cl ? c2b : c1b;
    float* __restrict__ sq           = cl ? sq2 : sq1;
    const float scale                = cl ? 1.0f : -2.0f;

    float4 cs = {0.f, 0.f, 0.f, 0.f};
    float4 cq = {0.f, 0.f, 0.f, 0.f};

    #pragma unroll 4
    for (int i = 0; i < 8; ++i) {
        const int row = blk * 64 + wave * 16 + i * 2 + half;
        float4 x = *reinterpret_cast<const float4*>(src + (size_t)row * DIMS + l32 * 4);
        B4 b4{__float2bfloat16(scale * x.x), __float2bfloat16(scale * x.y),
              __float2bfloat16(scale * x.z), __float2bfloat16(scale * x.w)};
        const int eoff = cl ? (l32 * 4) : ((l32 * 4) ^ ((row & 15) << 3));
        *reinterpret_cast<B4*>(dst + (size_t)row * DIMS + eoff) = b4;
        float s = x.x * x.x + x.y * x.y + x.z * x.z + x.w * x.w;
        #pragma unroll
        for (int m = 16; m; m >>= 1) s += __shfl_xor(s, m);   // within 32-lane half
        if (l32 == 0) sq[row] = s;
        cs.x += x.x; cs.y += x.y; cs.z += x.z; cs.w += x.w;
        cq.x += x.x * x.x; cq.y += x.y * x.y; cq.z += x.z * x.z; cq.w += x.w * x.w;
    }

    cs.x += __shfl_xor(cs.x, 32); cs.y += __shfl_xor(cs.y, 32);
    cs.z += __shfl_xor(cs.z, 32); cs.w += __shfl_xor(cs.w, 32);
    cq.x += __shfl_xor(cq.x, 32); cq.y += __shfl_xor(cq.y, 32);
    cq.z += __shfl_xor(cq.z, 32); cq.w += __shfl_xor(cq.w, 32);

    __shared__ float4 lds4[4][32];
    lds4[wave][l32] = cs;
    __syncthreads();
    if (tid < 32) {
        float4 a = lds4[0][tid], b = lds4[1][tid], c = lds4[2][tid], d = lds4[3][tid];
        float4 t = {a.x + b.x + c.x + d.x, a.y + b.y + c.y + d.y,
                    a.z + b.z + c.z + d.z, a.w + b.w + c.w + d.w};
        const int base = cl ? 32768 : 0;
        part[base + (4 * tid + 0) * 128 + blk] = t.x;
        part[base + (4 * tid + 1) * 128 + blk] = t.y;
        part[base + (4 * tid + 2) * 128 + blk] = t.z;
        part[base + (4 * tid + 3) * 128 + blk] = t.w;
    }
    __syncthreads();
    lds4[wave][l32] = cq;
    __syncthreads();
    if (tid < 32 && cl == 0) {
        float4 a = lds4[0][tid], b = lds4[1][tid], c = lds4[2][tid], d = lds4[3][tid];
        float4 t = {a.x + b.x + c.x + d.x, a.y + b.y + c.y + d.y,
                    a.z + b.z + c.z + d.z, a.w + b.w + c.w + d.w};
        part[16384 + (4 * tid + 0) * 128 + blk] = t.x;
        part[16384 + (4 * tid + 1) * 128 + blk] = t.y;
        part[16384 + (4 * tid + 2) * 128 + blk] = t.z;
        part[16384 + (4 * tid + 3) * 128 + blk] = t.w;
    }
}

// ---------------------------------------------------------------------------
// dist (measured session optimum, 46.87 us total): 512-thread blocks,
// grid 32 rg x 16 cg = 512 (2 blocks/CU, 64 KB LDS, 16 waves/CU = 4/SIMD).
// 8 waves share one 256-row A-tile (linear gload_lds of pre-swizzled c1b);
// each wave owns a distinct 64-col slice: b_u[4][4] = 64 VGPRs (asm-pinned;
// known ~16-reg spill tax — measured equivalent to every alternative:
// no-pin remat r20, AGPR-pin r22, smaller pin r18, both-LDS r16/r23).
// Per rt: 4 swizzled ds_read_b128 -> 16 MFMAs (C-in = sq2[col], c1b
// pre-scaled -2 -> acc = sq2 - 2*c1.c2); DPP xor-min; pmin write.
// swz = lo<<4 (full 4-bit row). pmin[row*128 + cg*8 + wv]: one write/slot.
// MFMA 16x16x32 bf16 layouts (validated: absmax 0.0):
//   A: row = lane&15, k = (lane>>4)*8 + j
//   B: col = lane&15, k = (lane>>4)*8 + j
//   D: col = lane&15, row = (lane>>4)*4 + r
// ---------------------------------------------------------------------------
__global__ __attribute__((amdgpu_flat_work_group_size(512, 512),
                          amdgpu_waves_per_eu(2, 4)))
void dist_k(const __hip_bfloat16* __restrict__ c1bs,   // swizzled
            const __hip_bfloat16* __restrict__ c2b,    // linear
            const float* __restrict__ sq2,
            float* __restrict__ pmin) {
    __shared__ uint4 smem4[4096];                      // 64 KB
    char* smem = (char*)smem4;

    const int tid  = threadIdx.x;
    const int lane = tid & 63;
    const int wv   = tid >> 6;            // 0..7
    const int lo = lane & 15;
    const int hi = lane >> 4;
    const int rg = blockIdx.x >> 4;       // 0..31 : 256-row group
    const int cg = blockIdx.x & 15;       // 0..15 : 512-col group
    const int row0 = rg * 256;
    const int col0 = cg * 512 + wv * 64;

    // Stage the 256-row A-tile once (linear copy of pre-swizzled c1b).
    {
        const char* gsrc = (const char*)c1bs + (size_t)row0 * 256;
        #pragma unroll
        for (int i = 0; i < 8; ++i) {
            const int off = i * 8192 + wv * 1024;      // wave-uniform LDS dest
            __builtin_amdgcn_global_load_lds(
                (const __attribute__((address_space(1))) unsigned int*)
                    (const void*)(gsrc + off + lane * 16),
                (__attribute__((address_space(3))) unsigned int*)
                    (void*)(smem + off),
                16, 0, 0);
        }
    }

    // B fragments: 4 col-tiles x 4 k-steps = 64 VGPRs, loaded once from L2.
    uint4 b_u[4][4];
    float sq2t[4];
    #pragma unroll
    for (int ct = 0; ct < 4; ++ct) {
        const int J = col0 + ct * 16 + lo;
        sq2t[ct] = sq2[J];
        #pragma unroll
        for (int ks = 0; ks < 4; ++ks)
            b_u[ct][ks] = *reinterpret_cast<const uint4*>(
                c2b + (size_t)J * DIMS + ks * 32 + hi * 8);
    }
    #pragma unroll
    for (int ct = 0; ct < 4; ++ct)
        #pragma unroll
        for (int ks = 0; ks < 4; ++ks)
            asm volatile("" : "+v"(b_u[ct][ks].x), "+v"(b_u[ct][ks].y),
                              "+v"(b_u[ct][ks].z), "+v"(b_u[ct][ks].w));

    asm volatile("s_waitcnt vmcnt(0)" ::: "memory");
    __syncthreads();

    const int swz = lo << 4;              // full 4-bit row swizzle (row&15 == lo)
    for (int rt = 0; rt < 16; ++rt) {
        bf16x8 a[4];
        #pragma unroll
        for (int ks = 0; ks < 4; ++ks) {
            const int boff = (rt * 16 + lo) * 256 + ((ks * 64 + hi * 16) ^ swz);
            a[ks] = *reinterpret_cast<const bf16x8*>(smem + boff);
        }

        float mrow[4] = {__builtin_inff(), __builtin_inff(),
                         __builtin_inff(), __builtin_inff()};

        #pragma unroll
        for (int ct = 0; ct < 4; ++ct) {
            f32x4 acc = {sq2t[ct], sq2t[ct], sq2t[ct], sq2t[ct]};
            #pragma unroll
            for (int ks = 0; ks < 4; ++ks)
                acc = __builtin_amdgcn_mfma_f32_16x16x32_bf16(
                    a[ks], __builtin_bit_cast(bf16x8, b_u[ct][ks]), acc, 0, 0, 0);
            #pragma unroll
            for (int r = 0; r < 4; ++r)
                mrow[r] = fminf(mrow[r], acc[r]);      // sq2 - 2*c1.c2
        }

        // 16-lane xor-min on the VALU (DPP), no DS traffic
        #pragma unroll
        for (int r = 0; r < 4; ++r) {
            float v = mrow[r];
            v = fmin_dpp<0xB1>(v);     // xor1
            v = fmin_dpp<0x4E>(v);     // xor2
            v = fmin_dpp<0x141>(v);    // row_half_mirror
            v = fmin_dpp<0x140>(v);    // row_mirror
            mrow[r] = v;
        }
        if (lo == 0) {
            #pragma unroll
            for (int r = 0; r < 4; ++r) {
                const int row = row0 + rt * 16 + hi * 4 + r;
                pmin[(size_t)row * 128 + cg * 8 + wv] = mrow[r];
            }
        }
    }
}

// ---------------------------------------------------------------------------
// tail (fused reduce + finalize): 32 blocks x 256 threads.
// Each block: (a) thread = one row -> min of 128 partials + sq1, block-sum
// -> rscratch[b]; (b) threads 0..11 each sum one column-stat job.
// Device-scope ticket: LAST block combines in fixed order -> out[0].
// cnt is zeroed by prep_k each call.
// ---------------------------------------------------------------------------
__global__ __launch_bounds__(256) void tail_k(const float* __restrict__ pmin,
                                              const float* __restrict__ sq1,
                                              const float* __restrict__ part,
                                              float* __restrict__ rscratch,
                                              float* __restrict__ cscratch,
                                              int* __restrict__ cnt,
                                              float* __restrict__ out) {
    __shared__ float red[256];
    __shared__ int is_last;
    const int b   = blockIdx.x;
    const int tid = threadIdx.x;

    // (a) row-min fold
    const int row = b * 256 + tid;
    const float4* p = reinterpret_cast<const float4*>(pmin + (size_t)row * 128);
    float4 m4 = p[0];
    #pragma unroll
    for (int i = 1; i < 32; ++i) {
        float4 v = p[i];
        m4.x = fminf(m4.x, v.x); m4.y = fminf(m4.y, v.y);
        m4.z = fminf(m4.z, v.z); m4.w = fminf(m4.w, v.w);
    }
    float m = fminf(fminf(m4.x, m4.y), fminf(m4.z, m4.w)) + sq1[row];

    red[tid] = m;
    __syncthreads();
    for (int off = 128; off; off >>= 1) {
        if (tid < off) red[tid] += red[tid + off];
        __syncthreads();
    }
    if (tid == 0) rscratch[b] = red[0];

    // (b) column-stat jobs
    if (tid < 12) {
        const int j = b * 12 + tid;
        const float4* q = reinterpret_cast<const float4*>(part + j * 128);
        float4 a = {0.f, 0.f, 0.f, 0.f};
        #pragma unroll 8
        for (int k = 0; k < 32; ++k) {
            float4 v = q[k];
            a.x += v.x; a.y += v.y; a.z += v.z; a.w += v.w;
        }
        cscratch[j] = a.x + a.y + a.z + a.w;
    }

    // ticket
    __threadfence();
    __syncthreads();
    if (tid == 0) {
        int old = atomicAdd(cnt, 1);
        is_last = (old == 31) ? 1 : 0;
    }
    __syncthreads();
    if (!is_last) return;
    __threadfence();

    // finisher: combine in fixed order (deterministic)
    float s = (tid < 32) ? atomicAdd(&rscratch[tid], 0.0f) : 0.0f;

    float mm = 0.f;
    if (tid < DIMS) {
        float cs1 = atomicAdd(&cscratch[tid], 0.0f);
        float cq1 = atomicAdd(&cscratch[128 + tid], 0.0f);
        float cs2 = atomicAdd(&cscratch[256 + tid], 0.0f);
        const float inv_n = 1.0f / N_ROWS;
        float m1 = cs1 * inv_n;
        float m2 = cs2 * inv_n;
        float d  = m1 - m2;
        float var = cq1 * inv_n - m1 * m1;
        mm = d * d + fmaxf(0.1f - var, 0.0f);
    }

    __syncthreads();           // red[] reuse
    red[tid] = s * (1.0f / N_ROWS) + mm * (1.0f / DIMS);
    __syncthreads();
    for (int off = 128; off; off >>= 1) {
        if (tid < off) red[tid] += red[tid + off];
        __syncthreads();
    }
    if (tid == 0) out[0] = red[0];
}

// ---------------------------------------------------------------------------
extern "C" void kernel_launch(void* const* d_in, const int* in_sizes, int n_in,
                              void* d_out, int out_size, void* d_ws, size_t ws_size,
                              hipStream_t stream) {
    (void)in_sizes; (void)n_in; (void)out_size; (void)ws_size;
    const float* c1 = (const float*)d_in[0];
    const float* c2 = (const float*)d_in[1];

    char* ws = (char*)d_ws;
    __hip_bfloat16* c1b = (__hip_bfloat16*)ws;                    // 2 MB (swizzled)
    __hip_bfloat16* c2b = (__hip_bfloat16*)(ws + (1u << 21));     // 2 MB
    float* sq1          = (float*)(ws + (1u << 22));              // 32 KB
    float* sq2          = sq1 + N_ROWS;                           // 32 KB
    float* pmin         = sq2 + N_ROWS;                           // 4 MB
    float* part         = pmin + (size_t)N_ROWS * 128;            // 192 KB
    float* rscratch     = part + 3 * 16384;                       // 128 B
    float* cscratch     = rscratch + 32;                          // 1.5 KB
    int*   cnt          = (int*)(cscratch + 384);                 // 4 B

    prep_k<<<256, 256, 0, stream>>>(c1, c2, c1b, c2b, sq1, sq2, part, cnt);
    dist_k<<<512, 512, 0, stream>>>(c1b, c2b, sq2, pmin);
    tail_k<<<32, 256, 0, stream>>>(pmin, sq1, part, rscratch, cscratch, cnt,
                                   (float*)d_out);
}